// Round 3
// baseline (47.446 us; speedup 1.0000x reference)
//
#include <hip/hip_runtime.h>

#define Bn 1024
#define Pn 128
#define Fn 512
#define Dn 256
#define THETA 1e-7f
#define BP (Bn * Pn)
#define S3 4            // F-split of the fused reduction kernel
#define FC3 (Fn / S3)   // 128

typedef short short8 __attribute__((ext_vector_type(8)));
typedef short short4v __attribute__((ext_vector_type(4)));
typedef float f32x4 __attribute__((ext_vector_type(4)));

__device__ __forceinline__ unsigned short f2bf(float f) {
    unsigned u = __builtin_bit_cast(unsigned, f);
    unsigned r = u + 0x7FFFu + ((u >> 16) & 1u);   // RNE (finite)
    return (unsigned short)(r >> 16);
}
__device__ __forceinline__ float bf2f(unsigned short h) {
    return __builtin_bit_cast(float, (unsigned)h << 16);
}

// ---------------------------------------------------------------------------
// Exact f32 GEMM (round-1, known-pass): C = [x; prototypes] @ fb^T.
// xf [B][F] row-major; pf [P][F] row-major (f-contig for M-pass + B-frags).
// ---------------------------------------------------------------------------
__global__ __launch_bounds__(256)
void gemm_feat(const float* __restrict__ x, const float* __restrict__ prot,
               const float* __restrict__ fb, float* __restrict__ xf,
               float* __restrict__ pf)
{
    __shared__ float As[64][68];
    __shared__ float Fs[64][68];
    const int tid = threadIdx.x;
    const int rb  = blockIdx.y * 64;
    const int cb  = blockIdx.x * 64;
    const int tx  = tid & 15;
    const int ty  = tid >> 4;
    const int lr  = tid >> 2;
    const int lk  = tid & 3;

    float acc[4][4] = {};

    for (int k0 = 0; k0 < Dn; k0 += 64) {
        #pragma unroll
        for (int q = 0; q < 4; ++q) {
            const int kk = lk + q * 4;
            const int r  = rb + lr;
            const float* asrc = (r < Bn) ? (x + (size_t)r * Dn)
                                         : (prot + (size_t)(r - Bn) * Dn);
            float4 av = *(const float4*)(asrc + k0 + kk * 4);
            float4 fv = *(const float4*)(fb + (size_t)(cb + lr) * Dn + k0 + kk * 4);
            As[kk*4+0][lr] = av.x; As[kk*4+1][lr] = av.y;
            As[kk*4+2][lr] = av.z; As[kk*4+3][lr] = av.w;
            Fs[kk*4+0][lr] = fv.x; Fs[kk*4+1][lr] = fv.y;
            Fs[kk*4+2][lr] = fv.z; Fs[kk*4+3][lr] = fv.w;
        }
        __syncthreads();
        #pragma unroll 8
        for (int k = 0; k < 64; ++k) {
            float4 a = *(const float4*)&As[k][ty * 4];
            float4 f = *(const float4*)&Fs[k][tx * 4];
            const float aa[4] = {a.x, a.y, a.z, a.w};
            const float ff[4] = {f.x, f.y, f.z, f.w};
            #pragma unroll
            for (int i = 0; i < 4; ++i)
                #pragma unroll
                for (int j = 0; j < 4; ++j)
                    acc[i][j] = fmaf(aa[i], ff[j], acc[i][j]);
        }
        __syncthreads();
    }

    #pragma unroll
    for (int i = 0; i < 4; ++i) {
        const int r = rb + ty * 4 + i;
        #pragma unroll
        for (int j = 0; j < 4; ++j) {
            const int c = cb + tx * 4 + j;
            if (r < Bn) xf[(size_t)r * Fn + c] = acc[i][j];
            else        pf[(size_t)(r - Bn) * Fn + c] = acc[i][j];
        }
    }
}

// ---------------------------------------------------------------------------
// Prep: from exact xf/pf build bf16 hi/lo splits of relu() and exact 0/1
// masks (bf16 1.0 = 0x3F80). One float4 per thread.
// ---------------------------------------------------------------------------
#define AG (Bn * Fn / 4)          // 131072
#define PG (Pn * Fn / 4)          // 16384

__global__ __launch_bounds__(256)
void prep(const float* __restrict__ xf, const float* __restrict__ pf,
          short* __restrict__ RXh, short* __restrict__ RXl, short* __restrict__ BX,
          short* __restrict__ RPh, short* __restrict__ RPl, short* __restrict__ BPm)
{
    const int g = blockIdx.x * 256 + threadIdx.x;
    const float* src;
    short *dh, *dl, *db;
    int off;
    if (g < AG) { src = xf + (size_t)g * 4; dh = RXh; dl = RXl; db = BX; off = g * 4; }
    else {
        const int g2 = g - AG;
        if (g2 >= PG) return;
        src = pf + (size_t)g2 * 4; dh = RPh; dl = RPl; db = BPm; off = g2 * 4;
    }
    const float4 v = *(const float4*)src;
    const float vv[4] = {v.x, v.y, v.z, v.w};
    short4v hi, lo, bm;
    #pragma unroll
    for (int c = 0; c < 4; ++c) {
        const float r = fmaxf(vv[c], 0.f);
        const unsigned short h = f2bf(r);
        hi[c] = (short)h;
        lo[c] = (short)f2bf(r - bf2f(h));
        bm[c] = (vv[c] > 0.f) ? (short)0x3F80 : (short)0;
    }
    *(short4v*)(dh + off) = hi;
    *(short4v*)(dl + off) = lo;
    *(short4v*)(db + off) = bm;
}

// ---------------------------------------------------------------------------
// Fused reduction over one F-chunk:
//  MFMA half: I = RX*RP^T, SXB = RX*BPm^T, SPB = BX*RP^T (bf16 hi/lo splits).
//    Block = 64b x 32p, 4 waves; wave w covers b-rows [bb+16w, +16), 2 p-frags.
//    A-frag lane l: row l&15, k=(l>>4)*8; C/D: col=l&15, row=(l>>4)*4+reg.
//  VALU half: M = sum_f max(min(xf,pf),0), exact f32, thread = 2b x 4p.
//  Outputs partI, partG(=alpha*SXB+beta*SPB), partM  [S3][B][P].
// ---------------------------------------------------------------------------
__global__ __launch_bounds__(256)
void tversky_fused(const float* __restrict__ xf, const float* __restrict__ pf,
                   const short* __restrict__ RXh, const short* __restrict__ RXl,
                   const short* __restrict__ BX,
                   const short* __restrict__ RPh, const short* __restrict__ RPl,
                   const short* __restrict__ BPm,
                   const float* __restrict__ alpha_p, const float* __restrict__ beta_p,
                   float* __restrict__ partI, float* __restrict__ partG,
                   float* __restrict__ partM)
{
    const int tid  = threadIdx.x;
    const int lane = tid & 63;
    const int wave = tid >> 6;
    const int bb   = blockIdx.x * 64;
    const int pb   = blockIdx.y * 32;
    const int s    = blockIdx.z;
    const int f0   = s * FC3;

    // ---------------- MFMA half ----------------
    const int arow = bb + wave * 16 + (lane & 15);
    const int kb   = (lane >> 4) * 8;

    f32x4 aI[2] = {};
    f32x4 aX[2] = {};
    f32x4 aP[2] = {};

    #pragma unroll
    for (int k0 = 0; k0 < FC3; k0 += 32) {
        const size_t ka = (size_t)arow * Fn + f0 + k0 + kb;
        const short8 axh = *(const short8*)(RXh + ka);
        const short8 axl = *(const short8*)(RXl + ka);
        const short8 abx = *(const short8*)(BX  + ka);
        #pragma unroll
        for (int j = 0; j < 2; ++j) {
            const int col = pb + j * 16 + (lane & 15);
            const size_t kbp = (size_t)col * Fn + f0 + k0 + kb;
            const short8 bph = *(const short8*)(RPh + kbp);
            const short8 bpl = *(const short8*)(RPl + kbp);
            const short8 bbm = *(const short8*)(BPm + kbp);
            aI[j] = __builtin_amdgcn_mfma_f32_16x16x32_bf16(axh, bph, aI[j], 0, 0, 0);
            aI[j] = __builtin_amdgcn_mfma_f32_16x16x32_bf16(axh, bpl, aI[j], 0, 0, 0);
            aI[j] = __builtin_amdgcn_mfma_f32_16x16x32_bf16(axl, bph, aI[j], 0, 0, 0);
            aX[j] = __builtin_amdgcn_mfma_f32_16x16x32_bf16(axh, bbm, aX[j], 0, 0, 0);
            aX[j] = __builtin_amdgcn_mfma_f32_16x16x32_bf16(axl, bbm, aX[j], 0, 0, 0);
            aP[j] = __builtin_amdgcn_mfma_f32_16x16x32_bf16(abx, bph, aP[j], 0, 0, 0);
            aP[j] = __builtin_amdgcn_mfma_f32_16x16x32_bf16(abx, bpl, aP[j], 0, 0, 0);
        }
    }

    const float alpha = *alpha_p;
    const float beta  = *beta_p;
    #pragma unroll
    for (int j = 0; j < 2; ++j) {
        const int pp = pb + j * 16 + (lane & 15);
        #pragma unroll
        for (int i = 0; i < 4; ++i) {
            const int rr = bb + wave * 16 + (lane >> 4) * 4 + i;
            const size_t idx = (size_t)s * BP + (size_t)rr * Pn + pp;
            partI[idx] = aI[j][i];
            partG[idx] = alpha * aX[j][i] + beta * aP[j][i];
        }
    }

    // ---------------- M half (exact f32) ----------------
    const int tx = tid & 7;
    const int ty = tid >> 3;
    const int p0 = pb + tx * 4;
    const int b0 = bb + ty * 2;

    float aM[2][4] = {};
    for (int f = f0; f < f0 + FC3; f += 4) {
        float4 pr[4];
        #pragma unroll
        for (int q = 0; q < 4; ++q)
            pr[q] = *(const float4*)(pf + (size_t)(p0 + q) * Fn + f);
        float4 xr[2];
        #pragma unroll
        for (int i = 0; i < 2; ++i)
            xr[i] = *(const float4*)(xf + (size_t)(b0 + i) * Fn + f);

        #pragma unroll
        for (int i = 0; i < 2; ++i) {
            const float xv[4] = {xr[i].x, xr[i].y, xr[i].z, xr[i].w};
            #pragma unroll
            for (int q = 0; q < 4; ++q) {
                const float pv[4] = {pr[q].x, pr[q].y, pr[q].z, pr[q].w};
                #pragma unroll
                for (int c = 0; c < 4; ++c)
                    aM[i][q] += fmaxf(fminf(xv[c], pv[c]), 0.f);
            }
        }
    }
    #pragma unroll
    for (int i = 0; i < 2; ++i)
        #pragma unroll
        for (int q = 0; q < 4; ++q)
            partM[(size_t)s * BP + (size_t)(b0 + i) * Pn + (p0 + q)] = aM[i][q];
}

// ---------------------------------------------------------------------------
// Epilogue: out = I / (I + G - (alpha+beta)*M + THETA)
// ---------------------------------------------------------------------------
__global__ __launch_bounds__(256)
void tversky_epi(const float* __restrict__ partI, const float* __restrict__ partG,
                 const float* __restrict__ partM,
                 const float* __restrict__ alpha_p, const float* __restrict__ beta_p,
                 float* __restrict__ out)
{
    const int idx = blockIdx.x * 256 + threadIdx.x;
    float I = 0.f, G = 0.f, M = 0.f;
    #pragma unroll
    for (int s = 0; s < S3; ++s) {
        I += partI[(size_t)s * BP + idx];
        G += partG[(size_t)s * BP + idx];
        M += partM[(size_t)s * BP + idx];
    }
    const float ab = *alpha_p + *beta_p;
    out[idx] = I / (I + G - ab * M + THETA);
}

extern "C" void kernel_launch(void* const* d_in, const int* in_sizes, int n_in,
                              void* d_out, int out_size, void* d_ws, size_t ws_size,
                              hipStream_t stream)
{
    const float* x     = (const float*)d_in[0];
    const float* prot  = (const float*)d_in[1];
    const float* fb    = (const float*)d_in[2];
    const float* alpha = (const float*)d_in[3];
    const float* beta  = (const float*)d_in[4];
    float* out = (float*)d_out;

    // ws layout (float units; every block 16B-aligned by construction)
    float* xf    = (float*)d_ws;                       // B*F
    float* pf    = xf + (size_t)Bn * Fn;               // P*F
    float* partI = pf + (size_t)Pn * Fn;               // S3*BP
    float* partG = partI + (size_t)S3 * BP;            // S3*BP
    float* partM = partG + (size_t)S3 * BP;            // S3*BP
    short* RXh   = (short*)(partM + (size_t)S3 * BP);  // B*F shorts
    short* RXl   = RXh + (size_t)Bn * Fn;
    short* BX    = RXl + (size_t)Bn * Fn;
    short* RPh   = BX  + (size_t)Bn * Fn;              // P*F shorts
    short* RPl   = RPh + (size_t)Pn * Fn;
    short* BPm   = RPl + (size_t)Pn * Fn;

    dim3 gg(Fn / 64, (Bn + Pn) / 64);                  // 8 x 18
    gemm_feat<<<gg, 256, 0, stream>>>(x, prot, fb, xf, pf);

    const int pg = (AG + PG + 255) / 256;              // 576 blocks
    prep<<<pg, 256, 0, stream>>>(xf, pf, RXh, RXl, BX, RPh, RPl, BPm);

    dim3 gf(Bn / 64, Pn / 32, S3);                     // 16 x 4 x 4 = 256
    tversky_fused<<<gf, 256, 0, stream>>>(xf, pf, RXh, RXl, BX, RPh, RPl, BPm,
                                          alpha, beta, partI, partG, partM);

    tversky_epi<<<BP / 256, 256, 0, stream>>>(partI, partG, partM, alpha, beta, out);
}